// Round 8
// baseline (242.276 us; speedup 1.0000x reference)
//
#include <hip/hip_runtime.h>
#include <stdint.h>

#define B_      16
#define F_      257
#define T_      8000
#define NB_     64
#define TT_     32
#define NTILES  250
#define TPC     2      // body tiles per chunk (2 x 32 = 64 frames)
#define NCHUNK  125    // 16 b x 125 chunks = 2000 blocks ~ 8 blocks/CU
#define WTILES  2      // warm-up tiles: 64 steps. Warm-up converges from BELOW
                       // (init_min is a min), so contraction is rise-dominated:
                       // mixed-regime ~0.907/step -> 0.907^64 ~ 2e-3 rel on nf,
                       // same order as the bf16-vnr quantization already passing.

typedef __attribute__((ext_vector_type(8))) short short8;
typedef __attribute__((ext_vector_type(4))) float floatx4;

__device__ __forceinline__ unsigned short f2bf(float x) {
    union { float f; unsigned u; } v; v.f = x;
    unsigned r = v.u + 0x7FFFu + ((v.u >> 16) & 1u);   // RNE
    return (unsigned short)(r >> 16);
}

// LDS tile: conceptual bf16 [t 0..31][f 0..255], physical uint16 index:
//   idx16(t,f) = t*256 + (f ^ (st(t)<<3)),  st(t) = ((t&3)<<2) | ((t>>2)&3)
// - einsum b128 frag loads stay contiguous + aligned (XOR hits bits >=3 only)
// - scan writes have t UNIFORM across the wave (register scan), f = lane-
//   consecutive -> consecutive uint16 -> 2-way, free.
// - st(t) == st(l15) for t = tt*16 + l15 since (tt*16)>>2 == 0 (mod 4).
__device__ __forceinline__ int stidx(int t, int f) {
    const int st = ((t & 3) << 2) | ((t >> 2) & 3);
    return t * 256 + (f ^ (st << 3));
}

// launch_bounds history: (256,8) caps arch-VGPR at 32 -> catastrophic spill
// (round 4). (256,4) caps at 64, which this kernel fits exactly (rounds 2/6).
// With TT=32 the LDS block is 16.9 KB -> 8 blocks/CU resident, 32 waves/CU,
// 8 waves x 64 VGPR = 512/SIMD. Rate model: fabric rate for the per-lane-row
// scatter scales with waves/CU (R7: 16w -> 2.7 TB/s, R6: 32w -> 3.7 TB/s);
// this config keeps 32 waves/CU while cutting issued bytes 394 -> 263 MB.
__global__ __launch_bounds__(256, 4) void vnr_fused_kernel(
    const float* __restrict__ mag, const float* __restrict__ fb,
    const float* __restrict__ p_ns, const float* __restrict__ p_rr,
    const float* __restrict__ p_rf, float* __restrict__ out)
{
    __shared__ unsigned short tile16[TT_ * 256];  // 16 KB -> 8 blocks/CU
    __shared__ float mag256s[TT_];                // row 256 staging (handler wave only)
    __shared__ float vnr256s[TT_];                // row 256 vnr for epilogue

    const int tid  = threadIdx.x;
    const int lane = tid & 63;
    const int w    = tid >> 6;          // wave 0..3
    const int l15  = tid & 15;
    const int q    = (tid & 63) >> 4;   // quad in wave

    const int bid = blockIdx.x;
    const int b   = bid & 15;
    const int c   = bid >> 4;           // chunk 0..124
    const int hw  = bid & 3;            // f=256 handler wave, rotated per block

    const float ns   = fabsf(p_ns[0]);
    const float rise = 1.0f / (1.0f + __expf(-p_rr[0]));
    const float fall = 1.0f / (1.0f + __expf(-p_rf[0]));

    const float* magp   = mag + (size_t)b * (size_t)F_ * (size_t)T_;
    const float* rowp   = magp + (size_t)tid * (size_t)T_;   // this thread's f-row
    const float* row256 = magp + (size_t)256 * (size_t)T_;

    // ---- A-operand fragments (fb) straight into VGPRs, bf16-packed ----
    // lane holds A[m = 16w + l15][f = 32*kt + 8q + j], j=0..7
    short8 afrag[8];
    {
        const float* fbrow = fb + (16 * w + l15) * F_;
        #pragma unroll
        for (int kt = 0; kt < 8; ++kt) {
            const int f0 = 32 * kt + 8 * q;
            short8 a;
            #pragma unroll
            for (int j = 0; j < 8; ++j) a[j] = (short)f2bf(fbrow[f0 + j]);
            afrag[kt] = a;
        }
    }
    // fb[:,256] for the scalar fixup: rows 16w + 4q + r  (matches D layout)
    float fb256[4];
    #pragma unroll
    for (int r = 0; r < 4; ++r) fb256[r] = fb[(16 * w + 4 * q + r) * F_ + 256];

    // ---- init_min over first 20 frames (exact, like reference) ----
    float mn = 1e30f;
    #pragma unroll
    for (int u = 0; u < 5; ++u) {                 // 5 x float4 = frames 0..19
        const float4 v = *(const float4*)&rowp[4 * u];
        mn = fminf(mn, fminf(fminf(v.x, v.y), fminf(v.z, v.w)));
    }
    const float initv  = fmaxf(mn, 1e-5f);
    const float floorv = 0.5f * initv;
    float nf = initv;

    const bool isH = (tid == (hw << 6));
    float nf256 = 0.f, floor256 = 0.f;
    if (isH) {
        float m2 = 1e30f;
        #pragma unroll
        for (int u = 0; u < 5; ++u) {
            const float4 v = *(const float4*)&row256[4 * u];
            m2 = fminf(m2, fminf(fminf(v.x, v.y), fminf(v.z, v.w)));
        }
        float iv = fmaxf(m2, 1e-5f);
        nf256 = iv; floor256 = 0.5f * iv;
    }

    const int bodyBeg = TPC * c;
    const int tileBeg = max(0, bodyBeg - WTILES);   // clamp -> exact for small c
    const int tileEnd = min(bodyBeg + TPC, NTILES);

    for (int tile = tileBeg; tile < tileEnd; ++tile) {
        const int t0 = tile * TT_;

        // ---- 4-deep rolling prefetch of own-row tile (16 VGPRs, no spill).
        //      First 4 issued before barrier-1 so they overlap the previous
        //      tile's einsum; remaining 4 issue inside the scan 4 ahead of use.
        float4 buf[4];
        #pragma unroll
        for (int u = 0; u < 4; ++u)
            buf[u] = *(const float4*)&rowp[t0 + 4 * u];
        // row-256 staging: one coalesced load by the handler wave; only that
        // wave reads it back -> same-wave LDS ordering, no barrier needed.
        if (w == hw && lane < TT_) mag256s[lane] = row256[t0 + lane];

        if (tile >= bodyBeg) {
            // ---------------- BODY tile ----------------
            __syncthreads();   // previous einsum done with tile16 / vnr256s
            {
                float nfl = nf;
                #pragma unroll
                for (int u = 0; u < 8; ++u) {                    // 8 x 4 = 32 frames
                    const float4 cur = buf[u & 3];               // static idx (unrolled)
                    if (u + 4 < 8)
                        buf[u & 3] = *(const float4*)&rowp[t0 + 4 * (u + 4)];
                    #pragma unroll
                    for (int k = 0; k < 4; ++k) {
                        const float x = (&cur.x)[k];
                        const float a = (x > nfl) ? rise : fall;
                        nfl = fmaxf(__builtin_fmaf(a, x - nfl, nfl), floorv);
                        const float vnr = x * __builtin_amdgcn_rcpf(ns * nfl + 1e-8f);
                        tile16[stidx(4 * u + k, tid)] = f2bf(vnr);   // t uniform: conflict-free
                    }
                }
                nf = nfl;
            }
            if (isH) {   // f = 256 sequence (fp32 column), 16-wide batched LDS reads
                float nl = nf256;
                #pragma unroll
                for (int jb = 0; jb < TT_; jb += 16) {
                    float xv[16];
                    #pragma unroll
                    for (int u2 = 0; u2 < 16; ++u2) xv[u2] = mag256s[jb + u2];
                    #pragma unroll
                    for (int u2 = 0; u2 < 16; ++u2) {
                        const float x = xv[u2];
                        const float a2 = (x > nl) ? rise : fall;
                        nl = fmaxf(__builtin_fmaf(a2, x - nl, nl), floor256);
                        vnr256s[jb + u2] = x * __builtin_amdgcn_rcpf(ns * nl + 1e-8f);
                    }
                }
                nf256 = nl;
            }
            __syncthreads();   // tile16 + vnr256s ready

            // ---- einsum: out[n,t] = tanh(0.1 * sum_f fb[n,f]*vnr[f,t]) via MFMA
            const int stl3 = ((((l15 & 3) << 2) | (l15 >> 2)) << 3);  // st(t)<<3
            floatx4 acc[2];
            #pragma unroll
            for (int tt = 0; tt < 2; ++tt) acc[tt] = (floatx4){0.f, 0.f, 0.f, 0.f};

            #pragma unroll
            for (int kt = 0; kt < 8; ++kt) {
                #pragma unroll
                for (int tt = 0; tt < 2; ++tt) {
                    const int t = tt * 16 + l15;
                    const short8* bp = (const short8*)
                        &tile16[t * 256 + ((32 * kt + 8 * q) ^ stl3)];
                    acc[tt] = __builtin_amdgcn_mfma_f32_16x16x32_bf16(afrag[kt], *bp, acc[tt], 0, 0, 0);
                }
            }

            const size_t outb = (size_t)b * NB_ * T_;
            #pragma unroll
            for (int tt = 0; tt < 2; ++tt) {
                const int t = tt * 16 + l15;
                const float v256 = vnr256s[t];
                #pragma unroll
                for (int r = 0; r < 4; ++r) {
                    const float s = acc[tt][r] + fb256[r] * v256;        // s >= 0
                    const float e = __expf(s * 0.2f);                    // e^(2*s/10)
                    const float y = 1.0f - 2.0f * __builtin_amdgcn_rcpf(e + 1.0f);  // tanh(s/10)
                    out[outb + (size_t)(16 * w + 4 * q + r) * T_ + (size_t)(t0 + t)] = y;
                }
            }
        } else {
            // ---------------- WARM tile: pure-register, no LDS tile, no barriers ----
            float nfl = nf;
            #pragma unroll
            for (int u = 0; u < 8; ++u) {
                const float4 cur = buf[u & 3];
                if (u + 4 < 8)
                    buf[u & 3] = *(const float4*)&rowp[t0 + 4 * (u + 4)];
                #pragma unroll
                for (int k = 0; k < 4; ++k) {
                    const float x = (&cur.x)[k];
                    const float a = (x > nfl) ? rise : fall;
                    nfl = fmaxf(__builtin_fmaf(a, x - nfl, nfl), floorv);
                }
            }
            nf = nfl;
            if (isH) {
                float nl = nf256;
                #pragma unroll
                for (int jb = 0; jb < TT_; jb += 16) {
                    float xv[16];
                    #pragma unroll
                    for (int u2 = 0; u2 < 16; ++u2) xv[u2] = mag256s[jb + u2];
                    #pragma unroll
                    for (int u2 = 0; u2 < 16; ++u2) {
                        const float x = xv[u2];
                        const float a2 = (x > nl) ? rise : fall;
                        nl = fmaxf(__builtin_fmaf(a2, x - nl, nl), floor256);
                    }
                }
                nf256 = nl;
            }
        }
    }
}

extern "C" void kernel_launch(void* const* d_in, const int* in_sizes, int n_in,
                              void* d_out, int out_size, void* d_ws, size_t ws_size,
                              hipStream_t stream) {
    (void)in_sizes; (void)n_in; (void)d_ws; (void)ws_size; (void)out_size;
    const float* mag = (const float*)d_in[0];
    const float* fb  = (const float*)d_in[1];
    const float* ns  = (const float*)d_in[2];
    const float* rr  = (const float*)d_in[3];
    const float* rf  = (const float*)d_in[4];
    float* out = (float*)d_out;

    dim3 grid(B_ * NCHUNK);   // 2000 blocks = 16 b x 125 chunks -> ~8 blocks/CU
    dim3 block(256);
    hipLaunchKernelGGL(vnr_fused_kernel, grid, block, 0, stream, mag, fb, ns, rr, rf, out);
}

// Round 9
// 239.917 us; speedup vs baseline: 1.0098x; 1.0098x over previous
//
#include <hip/hip_runtime.h>
#include <stdint.h>

#define B_      16
#define F_      257
#define T_      8000
#define NB_     64
#define TT_     32
#define NTILES  250
#define TPC     4      // body tiles per chunk (4 x 32 = 128 frames)
#define NCHUNK  63     // 16 b x 63 chunks = 1008 blocks ~ 1 generation
#define WTILES  2      // warm-up: 64 steps (validated R8: passes absmax)

typedef __attribute__((ext_vector_type(8))) short short8;
typedef __attribute__((ext_vector_type(4))) float floatx4;

__device__ __forceinline__ unsigned short f2bf(float x) {
    union { float f; unsigned u; } v; v.f = x;
    unsigned r = v.u + 0x7FFFu + ((v.u >> 16) & 1u);   // RNE
    return (unsigned short)(r >> 16);
}

// LDS tile: conceptual bf16 [t 0..31][f 0..255], physical uint16 index:
//   idx16(t,f) = t*256 + (f ^ (st(t)<<3)),  st(t) = ((t&3)<<2) | ((t>>2)&3)
// einsum b128 frags contiguous+aligned; scan writes t-uniform -> conflict-free.
__device__ __forceinline__ int stidx(int t, int f) {
    const int st = ((t & 3) << 2) | ((t >> 2) & 3);
    return t * 256 + (f ^ (st << 3));
}

// Phase-latency model (R0-R8): dur ~ 25us x barrier-phase-count; bytes and
// occupancy were flat levers. This version makes each phase stall-free:
// a tile's FULL 8-load set is issued one phase ahead (warm: rolling; body:
// after barrier-2, flying through the einsum, drained at next barrier-1).
// launch_bounds(256,3): VGPR cap ~168. History: (256,4)=64 spills depth-8
// (R1/R3); (256,8)=32 catastrophic (R4); 124 fits clean at (256,2) (R5).
__global__ __launch_bounds__(256, 3) void vnr_fused_kernel(
    const float* __restrict__ mag, const float* __restrict__ fb,
    const float* __restrict__ p_ns, const float* __restrict__ p_rr,
    const float* __restrict__ p_rf, float* __restrict__ out)
{
    __shared__ unsigned short tile16[TT_ * 256];  // 16 KB
    __shared__ float mag256s[TT_];                // row 256 staging (handler wave only)
    __shared__ float vnr256s[TT_];                // row 256 vnr for epilogue

    const int tid  = threadIdx.x;
    const int lane = tid & 63;
    const int w    = tid >> 6;          // wave 0..3
    const int l15  = tid & 15;
    const int q    = (tid & 63) >> 4;   // quad in wave

    const int bid = blockIdx.x;
    const int b   = bid & 15;
    const int c   = bid >> 4;           // chunk 0..62
    const int hw  = bid & 3;            // f=256 handler wave, rotated per block

    const float ns   = fabsf(p_ns[0]);
    const float rise = 1.0f / (1.0f + __expf(-p_rr[0]));
    const float fall = 1.0f / (1.0f + __expf(-p_rf[0]));

    const float* magp   = mag + (size_t)b * (size_t)F_ * (size_t)T_;
    const float* rowp   = magp + (size_t)tid * (size_t)T_;   // this thread's f-row
    const float* row256 = magp + (size_t)256 * (size_t)T_;

    // ---- A-operand fragments (fb) straight into VGPRs, bf16-packed ----
    short8 afrag[8];
    {
        const float* fbrow = fb + (16 * w + l15) * F_;
        #pragma unroll
        for (int kt = 0; kt < 8; ++kt) {
            const int f0 = 32 * kt + 8 * q;
            short8 a;
            #pragma unroll
            for (int j = 0; j < 8; ++j) a[j] = (short)f2bf(fbrow[f0 + j]);
            afrag[kt] = a;
        }
    }
    float fb256[4];
    #pragma unroll
    for (int r = 0; r < 4; ++r) fb256[r] = fb[(16 * w + 4 * q + r) * F_ + 256];

    // ---- init_min over first 20 frames (exact, like reference) ----
    float mn = 1e30f;
    #pragma unroll
    for (int u = 0; u < 5; ++u) {
        const float4 v = *(const float4*)&rowp[4 * u];
        mn = fminf(mn, fminf(fminf(v.x, v.y), fminf(v.z, v.w)));
    }
    const float initv  = fmaxf(mn, 1e-5f);
    const float floorv = 0.5f * initv;
    float nf = initv;

    const bool isH = (tid == (hw << 6));
    float nf256 = 0.f, floor256 = 0.f;
    if (isH) {
        float m2 = 1e30f;
        #pragma unroll
        for (int u = 0; u < 5; ++u) {
            const float4 v = *(const float4*)&row256[4 * u];
            m2 = fminf(m2, fminf(fminf(v.x, v.y), fminf(v.z, v.w)));
        }
        float iv = fmaxf(m2, 1e-5f);
        nf256 = iv; floor256 = 0.5f * iv;
    }

    const int bodyBeg = TPC * c;
    const int tileBeg = max(0, bodyBeg - WTILES);   // clamp -> exact for small c
    const int tileEnd = min(bodyBeg + TPC, NTILES);

    // ---- full-tile prefetch: buf holds the CURRENT tile's 8 float4 (32 VGPR),
    //      always issued one phase ahead of consumption.
    float4 buf[8];
    #pragma unroll
    for (int u = 0; u < 8; ++u)
        buf[u] = *(const float4*)&rowp[tileBeg * TT_ + 4 * u];

    for (int tile = tileBeg; tile < tileEnd; ++tile) {
        const int t0 = tile * TT_;
        const bool hasNext = (tile + 1 < tileEnd);

        // row-256 staging: coalesced load by the handler wave; only that wave
        // reads it back -> same-wave LDS ordering, no barrier needed.
        if (w == hw && lane < TT_) mag256s[lane] = row256[t0 + lane];

        if (tile >= bodyBeg) {
            // ---------------- BODY tile ----------------
            __syncthreads();   // barrier-1: drains this tile's prefetch (in
                               // flight since the previous phase) + protects
                               // tile16 from the previous einsum's readers
            {   // scan: consume registers only -> stall-free phase
                float nfl = nf;
                #pragma unroll
                for (int u = 0; u < 8; ++u) {
                    const float4 cur = buf[u];
                    #pragma unroll
                    for (int k = 0; k < 4; ++k) {
                        const float x = (&cur.x)[k];
                        const float a = (x > nfl) ? rise : fall;
                        nfl = fmaxf(__builtin_fmaf(a, x - nfl, nfl), floorv);
                        const float vnr = x * __builtin_amdgcn_rcpf(ns * nfl + 1e-8f);
                        tile16[stidx(4 * u + k, tid)] = f2bf(vnr);   // t uniform: conflict-free
                    }
                }
                nf = nfl;
            }
            if (isH) {   // f = 256 sequence (fp32 column), 16-wide batched LDS reads
                float nl = nf256;
                #pragma unroll
                for (int jb = 0; jb < TT_; jb += 16) {
                    float xv[16];
                    #pragma unroll
                    for (int u2 = 0; u2 < 16; ++u2) xv[u2] = mag256s[jb + u2];
                    #pragma unroll
                    for (int u2 = 0; u2 < 16; ++u2) {
                        const float x = xv[u2];
                        const float a2 = (x > nl) ? rise : fall;
                        nl = fmaxf(__builtin_fmaf(a2, x - nl, nl), floor256);
                        vnr256s[jb + u2] = x * __builtin_amdgcn_rcpf(ns * nl + 1e-8f);
                    }
                }
                nf256 = nl;
            }
            __syncthreads();   // barrier-2: tile16 + vnr256s ready

            // issue NEXT tile's full prefetch now: it flies through the einsum
            // below and drains at the next tile's barrier-1.
            if (hasNext) {
                #pragma unroll
                for (int u = 0; u < 8; ++u)
                    buf[u] = *(const float4*)&rowp[(t0 + TT_) + 4 * u];
            }

            // ---- einsum: out[n,t] = tanh(0.1 * sum_f fb[n,f]*vnr[f,t]) via MFMA
            const int stl3 = ((((l15 & 3) << 2) | (l15 >> 2)) << 3);  // st(t)<<3
            floatx4 acc[2];
            #pragma unroll
            for (int tt = 0; tt < 2; ++tt) acc[tt] = (floatx4){0.f, 0.f, 0.f, 0.f};

            #pragma unroll
            for (int kt = 0; kt < 8; ++kt) {
                #pragma unroll
                for (int tt = 0; tt < 2; ++tt) {
                    const int t = tt * 16 + l15;
                    const short8* bp = (const short8*)
                        &tile16[t * 256 + ((32 * kt + 8 * q) ^ stl3)];
                    acc[tt] = __builtin_amdgcn_mfma_f32_16x16x32_bf16(afrag[kt], *bp, acc[tt], 0, 0, 0);
                }
            }

            const size_t outb = (size_t)b * NB_ * T_;
            #pragma unroll
            for (int tt = 0; tt < 2; ++tt) {
                const int t = tt * 16 + l15;
                const float v256 = vnr256s[t];
                #pragma unroll
                for (int r = 0; r < 4; ++r) {
                    const float s = acc[tt][r] + fb256[r] * v256;        // s >= 0
                    const float e = __expf(s * 0.2f);                    // e^(2*s/10)
                    const float y = 1.0f - 2.0f * __builtin_amdgcn_rcpf(e + 1.0f);  // tanh(s/10)
                    out[outb + (size_t)(16 * w + 4 * q + r) * T_ + (size_t)(t0 + t)] = y;
                }
            }
        } else {
            // ---------------- WARM tile: pure-register, no LDS tile, no barriers.
            //      Rolling full-tile prefetch: consume slot u, refill with the
            //      next tile's slot u (stays in flight across the warm->body
            //      transition, drained at body's barrier-1).
            float nfl = nf;
            #pragma unroll
            for (int u = 0; u < 8; ++u) {
                const float4 cur = buf[u];
                if (hasNext)
                    buf[u] = *(const float4*)&rowp[(t0 + TT_) + 4 * u];
                #pragma unroll
                for (int k = 0; k < 4; ++k) {
                    const float x = (&cur.x)[k];
                    const float a = (x > nfl) ? rise : fall;
                    nfl = fmaxf(__builtin_fmaf(a, x - nfl, nfl), floorv);
                }
            }
            nf = nfl;
            if (isH) {
                float nl = nf256;
                #pragma unroll
                for (int jb = 0; jb < TT_; jb += 16) {
                    float xv[16];
                    #pragma unroll
                    for (int u2 = 0; u2 < 16; ++u2) xv[u2] = mag256s[jb + u2];
                    #pragma unroll
                    for (int u2 = 0; u2 < 16; ++u2) {
                        const float x = xv[u2];
                        const float a2 = (x > nl) ? rise : fall;
                        nl = fmaxf(__builtin_fmaf(a2, x - nl, nl), floor256);
                    }
                }
                nf256 = nl;
            }
        }
    }
}

extern "C" void kernel_launch(void* const* d_in, const int* in_sizes, int n_in,
                              void* d_out, int out_size, void* d_ws, size_t ws_size,
                              hipStream_t stream) {
    (void)in_sizes; (void)n_in; (void)d_ws; (void)ws_size; (void)out_size;
    const float* mag = (const float*)d_in[0];
    const float* fb  = (const float*)d_in[1];
    const float* ns  = (const float*)d_in[2];
    const float* rr  = (const float*)d_in[3];
    const float* rf  = (const float*)d_in[4];
    float* out = (float*)d_out;

    dim3 grid(B_ * NCHUNK);   // 1008 blocks = 16 b x 63 chunks ~ 1 generation
    dim3 block(256);
    hipLaunchKernelGGL(vnr_fused_kernel, grid, block, 0, stream, mag, fb, ns, rr, rf, out);
}